// Round 5
// baseline (259.492 us; speedup 1.0000x reference)
//
#include <hip/hip_runtime.h>

// NeuralGraphOutput: out[b,o] = sum_a mask[b,a] * relu( sum_f x[b,a,f] * W[f,o] + bias[o] )
//   x[b,a,:] = concat(atoms[b,a,0:64], sum_d bonds[b,a,d,0:16])   (80 features)
//   mask[b,a] = any(edges[b,a,d] != -1)
// B=2048, A=256, D=8, FA=64, FB=16, FP=256
//
// R5: R4 structure (half-molecule blocks, pre-swizzled W, partials+reduce) but
// compute loop swapped: outer nt (W-frags re-loaded from L2-hot ws per iter,
// 12 regs instead of 48), inner strips re-read A-frags from LDS. Cuts VGPR ->
// higher occupancy (target 20+ waves/CU; LDS 26KB allows 6 blocks/CU).

#define NB 2048
#define NA 256
#define ND 8
#define NFA 64
#define NFB 16
#define NF 80
#define NFP 256
#define PITCH 100          // bf16 elems per LDS row (200B stride: conflict-free b128)
#define AH 128             // atoms per block (half molecule)

#define PART_OFF    (64 * 1024)          // partials start at 64KB in ws

typedef __attribute__((ext_vector_type(8))) short short8;   // 8 bf16 = 4 VGPR
typedef __attribute__((ext_vector_type(4))) float f32x4;    // MFMA C/D

static __device__ __forceinline__ unsigned short f2bf(float f) {
    unsigned int u = __float_as_uint(f);
    return (unsigned short)((u + 0x7FFFu + ((u >> 16) & 1u)) >> 16);
}

// ---------- prep: W[80][256] fp32 -> bf16 B-fragments [ntg][ks][lane] ----------
__global__ void ngf_prep_w(const float* __restrict__ W, short8* __restrict__ wfrag)
{
    const int gid  = blockIdx.x;        // 0..47 = ntg*3 + ks
    const int nt   = gid / 3;
    const int ks   = gid % 3;
    const int lane = threadIdx.x;       // 0..63
    const int c    = nt * 16 + (lane & 15);
    short8 v;
    #pragma unroll
    for (int j = 0; j < 8; ++j) {
        const int k = ks * 32 + (lane >> 4) * 8 + j;
        float w = (k < NF) ? W[k * NFP + c] : 0.0f;
        v[j] = (short)f2bf(w);
    }
    wfrag[gid * 64 + lane] = v;
}

// ---------- main: half molecule per block ----------
__launch_bounds__(256, 5)
__global__ void ngf_mfma_kernel(const float4* __restrict__ atoms4,
                                const float4* __restrict__ bonds4,
                                const int4*   __restrict__ edges4,
                                const short8* __restrict__ wfrag,
                                const float*  __restrict__ bias,
                                float* __restrict__ part)
{
    const int bid  = blockIdx.x;         // 0..4095
    const int tid  = threadIdx.x;        // 0..255
    const int wave = tid >> 6;           // 0..3
    const int lane = tid & 63;
    const int lrow = lane & 15;          // A row / B col / C-D col
    const int lgrp = lane >> 4;          // k-group (A/B) / row-group (C/D)

    __shared__ unsigned short X[AH * PITCH];   // 25600 B
    __shared__ float maskf[AH];                // 512 B

    const size_t atomBase = (size_t)bid * AH;  // == mol*256 + half*128

    // ---------- stage X ----------
    // atoms: 128 atoms * 16 float4 = 2048 float4, 8 per thread, coalesced
    #pragma unroll
    for (int it = 0; it < 8; ++it) {
        const int flat = it * 256 + tid;
        const int a = flat >> 4, k4 = flat & 15;
        float4 v = atoms4[(atomBase + a) * 16 + k4];
        ushort4 o;
        o.x = f2bf(v.x); o.y = f2bf(v.y); o.z = f2bf(v.z); o.w = f2bf(v.w);
        *(ushort4*)&X[a * PITCH + k4 * 4] = o;
    }
    // bonds: sum over D=8; 4 threads per atom, 2 passes of 64 atoms
    #pragma unroll
    for (int p = 0; p < 2; ++p) {
        const int a = p * 64 + (tid >> 2);
        const int q = tid & 3;
        const float4* bp = bonds4 + (atomBase + a) * 32 + q;   // atom row = 32 float4
        float4 s = {0.0f, 0.0f, 0.0f, 0.0f};
        #pragma unroll
        for (int d = 0; d < 8; ++d) {
            float4 v = bp[d * 4];
            s.x += v.x; s.y += v.y; s.z += v.z; s.w += v.w;
        }
        ushort4 o;
        o.x = f2bf(s.x); o.y = f2bf(s.y); o.z = f2bf(s.z); o.w = f2bf(s.w);
        *(ushort4*)&X[a * PITCH + NFA + q * 4] = o;
    }
    // edges -> mask; zero K pad (k=80..95)
    if (tid < AH) {
        const int a = tid;
        int4 e0 = edges4[(atomBase + a) * 2];
        int4 e1 = edges4[(atomBase + a) * 2 + 1];
        bool any = (e0.x != -1) | (e0.y != -1) | (e0.z != -1) | (e0.w != -1)
                 | (e1.x != -1) | (e1.y != -1) | (e1.z != -1) | (e1.w != -1);
        maskf[a] = any ? 1.0f : 0.0f;
        uint4 z = {0u, 0u, 0u, 0u};
        *(uint4*)&X[a * PITCH + 80] = z;
        *(uint4*)&X[a * PITCH + 88] = z;
    }
    __syncthreads();

    // ---------- compute: outer nt (W re-loaded from L2-hot ws), inner strips ----------
    #pragma unroll 1
    for (int nt = 0; nt < 4; ++nt) {
        const int ntg = wave * 4 + nt;
        const short8 b0 = wfrag[(ntg * 3 + 0) * 64 + lane];
        const short8 b1 = wfrag[(ntg * 3 + 1) * 64 + lane];
        const short8 b2 = wfrag[(ntg * 3 + 2) * 64 + lane];
        const float  bv = bias[ntg * 16 + lrow];
        float cs = 0.0f;
        #pragma unroll
        for (int s = 0; s < 8; ++s) {
            const unsigned short* xr = &X[(s * 16 + lrow) * PITCH + lgrp * 8];
            short8 a0 = *(const short8*)(xr);          // k  0..31
            short8 a1 = *(const short8*)(xr + 32);     // k 32..63
            short8 a2 = *(const short8*)(xr + 64);     // k 64..95 (pad zeros)
            f32x4 acc = {0.0f, 0.0f, 0.0f, 0.0f};
            acc = __builtin_amdgcn_mfma_f32_16x16x32_bf16(a0, b0, acc, 0, 0, 0);
            acc = __builtin_amdgcn_mfma_f32_16x16x32_bf16(a1, b1, acc, 0, 0, 0);
            acc = __builtin_amdgcn_mfma_f32_16x16x32_bf16(a2, b2, acc, 0, 0, 0);
            float4 m4 = *(const float4*)&maskf[s * 16 + lgrp * 4];
            cs += fmaxf(acc[0] + bv, 0.0f) * m4.x
                + fmaxf(acc[1] + bv, 0.0f) * m4.y
                + fmaxf(acc[2] + bv, 0.0f) * m4.z
                + fmaxf(acc[3] + bv, 0.0f) * m4.w;
        }
        // reduce over the 4 row-groups, store partial for this col-tile
        cs += __shfl_xor(cs, 16, 64);
        cs += __shfl_xor(cs, 32, 64);
        if (lane < 16)
            part[(size_t)bid * NFP + ntg * 16 + lane] = cs;
    }
}

// ---------- reduce: out[mol][col] = part[2*mol][col] + part[2*mol+1][col] ----------
__global__ void ngf_reduce(const float* __restrict__ part, float* __restrict__ out)
{
    const int g   = blockIdx.x * 256 + threadIdx.x;   // 0..524287
    const int mol = g >> 8;
    const int col = g & 255;
    out[g] = part[(size_t)(2 * mol) * NFP + col] + part[(size_t)(2 * mol + 1) * NFP + col];
}

extern "C" void kernel_launch(void* const* d_in, const int* in_sizes, int n_in,
                              void* d_out, int out_size, void* d_ws, size_t ws_size,
                              hipStream_t stream) {
    const float4* atoms4 = (const float4*)d_in[0];
    const float4* bonds4 = (const float4*)d_in[1];
    const int4*   edges4 = (const int4*)d_in[2];
    const float*  W      = (const float*)d_in[3];
    const float*  bias   = (const float*)d_in[4];
    float* out = (float*)d_out;

    short8* wfrag = (short8*)d_ws;
    float*  part  = (float*)((char*)d_ws + PART_OFF);   // 4096*256 fp32 = 4 MB

    ngf_prep_w<<<48, 64, 0, stream>>>(W, wfrag);
    ngf_mfma_kernel<<<NB * 2, 256, 0, stream>>>(atoms4, bonds4, edges4, wfrag, bias, part);
    ngf_reduce<<<2048, 256, 0, stream>>>(part, out);
}

// Round 6
// 89.483 us; speedup vs baseline: 2.8999x; 2.8999x over previous
//
#include <hip/hip_runtime.h>
#include <hip/hip_bf16.h>

// NeuralGraphOutput: out[b,o] = sum_a mask[b,a] * relu( sum_f x[b,a,f] * W[f,o] + bias[o] )
//   x[b,a,:] = concat(atoms[b,a,0:64], sum_d bonds[b,a,d,0:16])   (80 features)
//   mask[b,a] = any(edges[b,a,d] != -1)
// B=2048, A=256, D=8, FA=64, FB=16, FP=256
//
// R6 = R4 structure (best so far) + hardware packed bf16 conversion.
//  - half-molecule blocks: 4096 x 256 thr, LDS 26KB
//  - W pre-swizzled to MFMA B-fragment layout once (prep kernel), loaded to
//    regs in the PROLOGUE (R5 lesson: per-iter reloads L2-miss under stream
//    pressure, +290MB HBM fetch)
//  - fp32->bf16 via __float22bfloat162_rn pairs -> v_cvt_pk_bf16_f32 (1 op / 2
//    elems instead of ~4 ops/elem manual RNE)
//  - partial col-sums to ws, tiny reduce kernel

#define NB 2048
#define NA 256
#define ND 8
#define NFA 64
#define NFB 16
#define NF 80
#define NFP 256
#define PITCH 100          // bf16 elems per LDS row (200B stride: conflict-free b128)
#define AH 128             // atoms per block (half molecule)

#define PART_OFF    (64 * 1024)          // partials start at 64KB in ws

typedef __attribute__((ext_vector_type(8))) short short8;   // 8 bf16 = 4 VGPR
typedef __attribute__((ext_vector_type(4))) float f32x4;    // MFMA C/D

static __device__ __forceinline__ unsigned int pk2bf(float lo, float hi) {
    // packed RNE fp32->bf16 pair; compiler emits v_cvt_pk_bf16_f32
    __hip_bfloat162 h = __float22bfloat162_rn(float2{lo, hi});
    return *reinterpret_cast<unsigned int*>(&h);
}

static __device__ __forceinline__ unsigned short f2bf(float f) {
    unsigned int u = __float_as_uint(f);
    return (unsigned short)((u + 0x7FFFu + ((u >> 16) & 1u)) >> 16);
}

// ---------- prep: W[80][256] fp32 -> bf16 B-fragments [ntg][ks][lane] ----------
__global__ void ngf_prep_w(const float* __restrict__ W, short8* __restrict__ wfrag)
{
    const int gid  = blockIdx.x;        // 0..47 = ntg*3 + ks
    const int nt   = gid / 3;
    const int ks   = gid % 3;
    const int lane = threadIdx.x;       // 0..63
    const int c    = nt * 16 + (lane & 15);
    short8 v;
    #pragma unroll
    for (int j = 0; j < 8; ++j) {
        const int k = ks * 32 + (lane >> 4) * 8 + j;
        float w = (k < NF) ? W[k * NFP + c] : 0.0f;
        v[j] = (short)f2bf(w);
    }
    wfrag[gid * 64 + lane] = v;
}

// ---------- main: half molecule per block ----------
__launch_bounds__(256, 4)
__global__ void ngf_mfma_kernel(const float4* __restrict__ atoms4,
                                const float4* __restrict__ bonds4,
                                const int4*   __restrict__ edges4,
                                const short8* __restrict__ wfrag,
                                const float*  __restrict__ bias,
                                float* __restrict__ part)
{
    const int bid  = blockIdx.x;         // 0..4095
    const int tid  = threadIdx.x;        // 0..255
    const int wave = tid >> 6;           // 0..3
    const int lane = tid & 63;
    const int lrow = lane & 15;          // A row / B col / C-D col
    const int lgrp = lane >> 4;          // k-group (A/B) / row-group (C/D)

    __shared__ unsigned short X[AH * PITCH];   // 25600 B
    __shared__ float maskf[AH];                // 512 B

    const size_t atomBase = (size_t)bid * AH;  // == mol*256 + half*128

    // ---------- W fragments: prologue, coalesced 16B loads (L2-hot) ----------
    short8 bf[3][4];
    float  bia[4];
    #pragma unroll
    for (int nt = 0; nt < 4; ++nt) {
        const int ntg = wave * 4 + nt;
        bia[nt] = bias[ntg * 16 + lrow];
        #pragma unroll
        for (int ks = 0; ks < 3; ++ks)
            bf[ks][nt] = wfrag[(ntg * 3 + ks) * 64 + lane];
    }

    // ---------- stage X ----------
    // atoms: 128 atoms * 16 float4 = 2048 float4, 8 per thread, coalesced
    #pragma unroll
    for (int it = 0; it < 8; ++it) {
        const int flat = it * 256 + tid;
        const int a = flat >> 4, k4 = flat & 15;
        float4 v = atoms4[(atomBase + a) * 16 + k4];
        uint2 o;
        o.x = pk2bf(v.x, v.y);
        o.y = pk2bf(v.z, v.w);
        *(uint2*)&X[a * PITCH + k4 * 4] = o;
    }
    // bonds: sum over D=8; 4 threads per atom, 2 passes of 64 atoms
    #pragma unroll
    for (int p = 0; p < 2; ++p) {
        const int a = p * 64 + (tid >> 2);
        const int q = tid & 3;
        const float4* bp = bonds4 + (atomBase + a) * 32 + q;   // atom row = 32 float4
        float4 s = {0.0f, 0.0f, 0.0f, 0.0f};
        #pragma unroll
        for (int d = 0; d < 8; ++d) {
            float4 v = bp[d * 4];
            s.x += v.x; s.y += v.y; s.z += v.z; s.w += v.w;
        }
        uint2 o;
        o.x = pk2bf(s.x, s.y);
        o.y = pk2bf(s.z, s.w);
        *(uint2*)&X[a * PITCH + NFA + q * 4] = o;
    }
    // edges -> mask; zero K pad (k=80..95)
    if (tid < AH) {
        const int a = tid;
        int4 e0 = edges4[(atomBase + a) * 2];
        int4 e1 = edges4[(atomBase + a) * 2 + 1];
        bool any = (e0.x != -1) | (e0.y != -1) | (e0.z != -1) | (e0.w != -1)
                 | (e1.x != -1) | (e1.y != -1) | (e1.z != -1) | (e1.w != -1);
        maskf[a] = any ? 1.0f : 0.0f;
        uint4 z = {0u, 0u, 0u, 0u};
        *(uint4*)&X[a * PITCH + 80] = z;
        *(uint4*)&X[a * PITCH + 88] = z;
    }
    __syncthreads();

    // ---------- compute: 8 strips of 16 atoms; wave owns 64 output cols ----------
    float colsum[4] = {0.0f, 0.0f, 0.0f, 0.0f};
    #pragma unroll 2
    for (int s = 0; s < 8; ++s) {
        const int row = s * 16 + lrow;
        const unsigned short* xr = &X[row * PITCH + lgrp * 8];
        short8 a0 = *(const short8*)(xr);          // k  0..31
        short8 a1 = *(const short8*)(xr + 32);     // k 32..63
        short8 a2 = *(const short8*)(xr + 64);     // k 64..95 (pad zeros)
        float4 m4 = *(const float4*)&maskf[s * 16 + lgrp * 4];
        #pragma unroll
        for (int nt = 0; nt < 4; ++nt) {
            f32x4 acc = {0.0f, 0.0f, 0.0f, 0.0f};
            acc = __builtin_amdgcn_mfma_f32_16x16x32_bf16(a0, bf[0][nt], acc, 0, 0, 0);
            acc = __builtin_amdgcn_mfma_f32_16x16x32_bf16(a1, bf[1][nt], acc, 0, 0, 0);
            acc = __builtin_amdgcn_mfma_f32_16x16x32_bf16(a2, bf[2][nt], acc, 0, 0, 0);
            const float bv = bia[nt];
            colsum[nt] += fmaxf(acc[0] + bv, 0.0f) * m4.x
                        + fmaxf(acc[1] + bv, 0.0f) * m4.y
                        + fmaxf(acc[2] + bv, 0.0f) * m4.z
                        + fmaxf(acc[3] + bv, 0.0f) * m4.w;
        }
    }

    // ---------- reduce row-groups, store partial ----------
    #pragma unroll
    for (int nt = 0; nt < 4; ++nt) {
        float v = colsum[nt];
        v += __shfl_xor(v, 16, 64);
        v += __shfl_xor(v, 32, 64);
        if (lane < 16)
            part[(size_t)bid * NFP + (wave * 4 + nt) * 16 + lane] = v;
    }
}

// ---------- reduce: out[mol][col] = part[2*mol][col] + part[2*mol+1][col] ----------
__global__ void ngf_reduce(const float* __restrict__ part, float* __restrict__ out)
{
    const int g   = blockIdx.x * 256 + threadIdx.x;   // 0..524287
    const int mol = g >> 8;
    const int col = g & 255;
    out[g] = part[(size_t)(2 * mol) * NFP + col] + part[(size_t)(2 * mol + 1) * NFP + col];
}

extern "C" void kernel_launch(void* const* d_in, const int* in_sizes, int n_in,
                              void* d_out, int out_size, void* d_ws, size_t ws_size,
                              hipStream_t stream) {
    const float4* atoms4 = (const float4*)d_in[0];
    const float4* bonds4 = (const float4*)d_in[1];
    const int4*   edges4 = (const int4*)d_in[2];
    const float*  W      = (const float*)d_in[3];
    const float*  bias   = (const float*)d_in[4];
    float* out = (float*)d_out;

    short8* wfrag = (short8*)d_ws;
    float*  part  = (float*)((char*)d_ws + PART_OFF);   // 4096*256 fp32 = 4 MB

    ngf_prep_w<<<48, 64, 0, stream>>>(W, wfrag);
    ngf_mfma_kernel<<<NB * 2, 256, 0, stream>>>(atoms4, bonds4, edges4, wfrag, bias, part);
    ngf_reduce<<<2048, 256, 0, stream>>>(part, out);
}